// Round 1
// baseline (119.726 us; speedup 1.0000x reference)
//
#include <hip/hip_runtime.h>
#include <math.h>

// PrecisionFocusedLoss: mean over B of ce(logits, t) * (1 + 3*penalty)
//   penalty: FN (t==1, p==0) -> 1.0 ; FP (t==0, p==1) -> 5.0 ; else 0.1
//   => weight: FN -> 4.0 ; FP -> 16.0 ; else 1.3
// B = 8388608, C = 2. Memory-bound: 96 MiB in, 4 B out.

#define LOSS_BATCH 8388608
#define LOSS_GRID  2048
#define LOSS_BLOCK 256

__device__ __forceinline__ float sample_loss(float l0, float l1, int t) {
    // log-sum-exp over 2 classes, numerically stable
    float m   = fmaxf(l0, l1);
    float d   = fabsf(l0 - l1);
    float lse = m + log1pf(__expf(-d));
    float ce  = lse - (t ? l1 : l0);
    // argmax with first-index tie-break: pred=1 iff l1 > l0
    bool p1 = l1 > l0;
    float w;
    if (t == 1 && !p1)      w = 4.0f;   // false negative: 1 + 3*1.0
    else if (t == 0 && p1)  w = 16.0f;  // false positive: 1 + 3*5.0
    else                    w = 1.3f;   // 1 + 3*0.1
    return ce * w;
}

__global__ __launch_bounds__(LOSS_BLOCK) void loss_partial_kernel(
        const float4* __restrict__ logits4,   // 2 samples per float4
        const int4*   __restrict__ tgt4,      // 4 targets per int4
        float*        __restrict__ partials)  // [LOSS_GRID]
{
    const int nquads = LOSS_BATCH / 4;  // 4 samples per iteration
    float acc = 0.0f;
    for (int q = blockIdx.x * blockDim.x + threadIdx.x; q < nquads;
         q += gridDim.x * blockDim.x) {
        float4 a = logits4[2 * q];       // samples 4q, 4q+1
        float4 b = logits4[2 * q + 1];   // samples 4q+2, 4q+3
        int4   t = tgt4[q];
        acc += sample_loss(a.x, a.y, t.x);
        acc += sample_loss(a.z, a.w, t.y);
        acc += sample_loss(b.x, b.y, t.z);
        acc += sample_loss(b.z, b.w, t.w);
    }
    // wave-64 reduction
    #pragma unroll
    for (int off = 32; off > 0; off >>= 1)
        acc += __shfl_down(acc, off, 64);
    __shared__ float smem[LOSS_BLOCK / 64];
    int lane = threadIdx.x & 63;
    int wid  = threadIdx.x >> 6;
    if (lane == 0) smem[wid] = acc;
    __syncthreads();
    if (threadIdx.x == 0) {
        float s = 0.0f;
        #pragma unroll
        for (int i = 0; i < LOSS_BLOCK / 64; ++i) s += smem[i];
        partials[blockIdx.x] = s;
    }
}

__global__ __launch_bounds__(256) void loss_final_kernel(
        const float* __restrict__ partials, float* __restrict__ out)
{
    double acc = 0.0;
    for (int i = threadIdx.x; i < LOSS_GRID; i += blockDim.x)
        acc += (double)partials[i];
    #pragma unroll
    for (int off = 32; off > 0; off >>= 1)
        acc += __shfl_down(acc, off, 64);
    __shared__ double smem[4];
    int lane = threadIdx.x & 63;
    int wid  = threadIdx.x >> 6;
    if (lane == 0) smem[wid] = acc;
    __syncthreads();
    if (threadIdx.x == 0) {
        double s = smem[0] + smem[1] + smem[2] + smem[3];
        out[0] = (float)(s / (double)LOSS_BATCH);
    }
}

extern "C" void kernel_launch(void* const* d_in, const int* in_sizes, int n_in,
                              void* d_out, int out_size, void* d_ws, size_t ws_size,
                              hipStream_t stream) {
    const float4* logits4 = (const float4*)d_in[0];
    const int4*   tgt4    = (const int4*)d_in[1];
    float* partials = (float*)d_ws;           // LOSS_GRID floats = 8 KB
    float* out      = (float*)d_out;

    loss_partial_kernel<<<LOSS_GRID, LOSS_BLOCK, 0, stream>>>(logits4, tgt4, partials);
    loss_final_kernel<<<1, 256, 0, stream>>>(partials, out);
}